// Round 1
// 136.400 us; speedup vs baseline: 1.0877x; 1.0877x over previous
//
#include <hip/hip_runtime.h>
#include <math.h>

#define ROW_C 512
#define NBIN 2048
#define NPACK (NBIN / 2)   // two 16-bit counters per int -> 1024 ints = 4KB/wave

// One wave per row, 8 elements/lane. Selection of the K-th largest for
// K in {256,341,384,409}:
//  1. value-uniform 2048-bin histogram over octave [8,16) (clamp +-3.90625,
//     +12.0 -> bin width 1/256; bits [22:12] are monotone). Packed u16x2
//     counters, per-wave LDS, XOR-swizzled so int4 reads/writes are
//     bank-conflict-free.
//  2. NO full prefix: per-lane packed totals of its 32 raw bins + one 6-step
//     cross-lane scan. 4 ballots locate each rank's owner lane; lanes 0..3
//     read the owner's 16 raw words (independent b128 loads) and run a
//     branchless in-register crossing scan -> threshold bin, R-within-bin,
//     and the exact "whole bin admitted" predicate (pref[bsel-1] == T-1).
//  3. all-in ranks (~60%): membership is exactly bin >= bsel (bins monotone
//     in value) -> no tail loop at all.
//  4. remaining ranks: exact tail via iterative wave-max on the monotone
//     uint32 key; index tie-break matches jax.lax.top_k.
// Softmax shift term omitted (shift-invariant, |x| small). No __syncthreads
// (wave-private LDS, in-order DS pipe).
__global__ __launch_bounds__(256) void topk_ms_kernel(
    const float* __restrict__ attn,
    const float* __restrict__ w1p, const float* __restrict__ w2p,
    const float* __restrict__ w3p, const float* __restrict__ w4p,
    float* __restrict__ out)
{
    __shared__ __align__(16) unsigned hist_all[4][NPACK];

    const int lane = threadIdx.x & 63;
    const int wv   = threadIdx.x >> 6;
    unsigned* h = hist_all[wv];
    int4* hv = (int4*)h;

    const long long row  = (long long)blockIdx.x * 4 + wv;
    const long long base = row * ROW_C + lane * 8;

    const float4 A = *reinterpret_cast<const float4*>(attn + base);
    const float4 B = *reinterpret_cast<const float4*>(attn + base + 4);
    const float orig[8] = {A.x, A.y, A.z, A.w, B.x, B.y, B.z, B.w};

    unsigned key[8];
    int bin[8];
    float eo[8];
    #pragma unroll
    for (int s = 0; s < 8; ++s) {
        const unsigned u = __float_as_uint(orig[s]);
        key[s] = (u & 0x80000000u) ? ~u : (u | 0x80000000u);  // order-isomorphic
        // octave [8,16): clamp to +-3.90625 (exact), +12.0 -> y in [8.09375, 15.90625]
        const float y = fminf(fmaxf(orig[s], -3.90625f), 3.90625f) + 12.0f;
        bin[s] = (int)((__float_as_uint(y) >> 12) & 0x7FFu);   // monotone, width 1/256
        eo[s] = __expf(orig[s]);
    }

    // ---- zero histogram (1024 ints, conflict-free int4 stores) ----
    {
        const int4 z = make_int4(0, 0, 0, 0);
        hv[lane] = z; hv[lane + 64] = z; hv[lane + 128] = z; hv[lane + 192] = z;
    }

    // ---- histogram: packed atomic adds, swizzled addressing ----
    // logical word j -> physical j ^ (bits[7:5] -> [4:2]); preserves 4-int blocks.
    #pragma unroll
    for (int s = 0; s < 8; ++s) {
        const int j  = bin[s] >> 1;
        const int ph = j ^ ((j >> 3) & 0x1C);
        atomicAdd(&h[ph], (bin[s] & 1) ? 0x10000u : 1u);
    }

    // ---- per-lane raw totals of own 32 bins (no full prefix needed) ----
    unsigned ps = 0;
    #pragma unroll
    for (int k = 0; k < 4; ++k) {
        const int b  = 4 * lane + k;
        const int pb = b ^ ((b >> 3) & 7);
        const int4 v = hv[pb];
        ps += (unsigned)v.x + (unsigned)v.y + (unsigned)v.z + (unsigned)v.w;
    }
    const unsigned tot = (ps & 0xFFFFu) + (ps >> 16);

    // cross-lane inclusive scan of lane totals
    unsigned incl = tot;
    #pragma unroll
    for (int off = 1; off < 64; off <<= 1) {
        const unsigned t = __shfl_up(incl, off, 64);
        if (lane >= off) incl += t;
    }
    const unsigned excl = incl - tot;

    // ---- owner lane per rank: first lane with incl >= T, T = 513-K ----
    const unsigned long long Ba = __ballot(incl >= 257u);
    const unsigned long long Bb = __ballot(incl >= 172u);
    const unsigned long long Bc = __ballot(incl >= 129u);
    const unsigned long long Bd = __ballot(incl >= 104u);
    const int l0 = __ffsll(Ba) - 1, l1 = __ffsll(Bb) - 1,
              l2 = __ffsll(Bc) - 1, l3 = __ffsll(Bd) - 1;

    const int lsel = (lane == 0) ? l0 : (lane == 1) ? l1 : (lane == 2) ? l2 : l3;
    const int Tr   = (lane == 0) ? 257 : (lane == 1) ? 172 : (lane == 2) ? 129 : 104;
    const int Kr   = (lane == 0) ? 256 : (lane == 1) ? 341 : (lane == 2) ? 384 : 409;
    const unsigned exl = __shfl(excl, lsel & 63, 64);

    // ---- 4-lane in-register crossing scan over the owner's 16 raw words ----
    unsigned brR = 0u;
    if (lane < 4) {
        const int Tl = Tr - (int)exl;                 // local target, 1..512
        const unsigned T16 = (unsigned)Tl << 16;
        const int jbase = lsel << 4;                  // owner's first word index
        const int xr = ((lsel >> 1) & 7) << 2;        // swizzle XOR (const per block)
        unsigned w[16];
        #pragma unroll
        for (int q = 0; q < 4; ++q) {
            const int pw = ((jbase + (q << 2)) ^ xr) >> 2;   // int4 index
            const int4 v = hv[pw];
            w[4*q+0] = (unsigned)v.x; w[4*q+1] = (unsigned)v.y;
            w[4*q+2] = (unsigned)v.z; w[4*q+3] = (unsigned)v.w;
        }
        unsigned run = 0, pcap = 0, rcap = 0; int jcap = 0; bool found = false;
        #pragma unroll
        for (int j = 0; j < 16; ++j) {
            // packed local prefix: lo = run+cnt_even, hi = run+cnt_even+cnt_odd
            const unsigned p = (w[j] + (w[j] << 16)) + (run + (run << 16));
            const bool ge   = (p >= T16);             // hi-half >= Tl
            const bool take = ge && !found;
            pcap = take ? p   : pcap;
            rcap = take ? run : rcap;                 // prefix before this word
            jcap = take ? j   : jcap;
            found = found || ge;
            run = p >> 16;
        }
        const int  lo   = (int)(pcap & 0xFFFFu);
        const bool ev   = (lo >= Tl);                 // crossing at even bin?
        const int  bsel = (lsel << 5) + (jcap << 1) + (ev ? 0 : 1);
        const int  locp = ev ? lo : (int)(pcap >> 16);   // local pref at bsel
        const int  prvp = ev ? (int)rcap : lo;           // local pref at bsel-1
        const int  R    = Kr - 512 + (int)exl + locp;    // rank within bin, >=1
        const unsigned allin = (prvp == Tl - 1) ? 1u : 0u;  // R == cnt(bsel)
        brR = ((unsigned)bsel << 17) | (allin << 16) | (unsigned)R;
    }

    int br_[4], Rr_[4], al_[4];
    #pragma unroll
    for (int r = 0; r < 4; ++r) {
        const unsigned v = __shfl(brR, r, 64);
        br_[r] = (int)(v >> 17);
        al_[r] = (int)((v >> 16) & 1u);
        Rr_[r] = (int)(v & 0xFFFFu);
    }

    // ---- exact tail only for ranks where the bin is partially admitted ----
    unsigned tk[4]; int need[4], cnteq[4];
    #pragma unroll
    for (int r = 0; r < 4; ++r) {
        tk[r] = 0u; need[r] = 0; cnteq[r] = 0;
        if (!al_[r]) {                       // wave-uniform branch
            unsigned cm[8];
            #pragma unroll
            for (int s = 0; s < 8; ++s)
                cm[s] = (bin[s] == br_[r]) ? key[s] : 0u;
            int R = Rr_[r];
            unsigned t; int c;
            while (true) {
                unsigned mk = cm[0];
                #pragma unroll
                for (int s = 1; s < 8; ++s) mk = (cm[s] > mk) ? cm[s] : mk;
                #pragma unroll
                for (int off = 32; off >= 1; off >>= 1) {
                    const unsigned o = __shfl_xor(mk, off, 64);
                    mk = (o > mk) ? o : mk;
                }
                t = mk;
                c = 0;
                #pragma unroll
                for (int s = 0; s < 8; ++s)
                    c += (int)__popcll(__ballot(cm[s] == t));
                if (c >= R) break;
                R -= c;
                #pragma unroll
                for (int s = 0; s < 8; ++s)
                    if (cm[s] == t) cm[s] = 0u;
            }
            tk[r] = t; need[r] = R; cnteq[r] = c;
        }
    }

    // ---- membership flags ----
    int fl[8] = {0, 0, 0, 0, 0, 0, 0, 0};
    #pragma unroll
    for (int r = 0; r < 4; ++r) {
        if (al_[r]) {                         // whole threshold bin admitted:
            const int bb = br_[r];            // membership is exactly bin >= bsel
            #pragma unroll
            for (int s = 0; s < 8; ++s)
                fl[s] |= ((int)(bin[s] >= bb)) << r;
        } else if (need[r] == cnteq[r]) {     // all ties admitted (common case)
            const unsigned t = tk[r];
            #pragma unroll
            for (int s = 0; s < 8; ++s)
                fl[s] |= ((int)(key[s] >= t)) << r;
        } else {                              // admit lowest original indices
            const unsigned t = tk[r];
            const unsigned long long ltm = (1ull << lane) - 1ull;
            int basec = 0;
            #pragma unroll
            for (int s = 0; s < 8; ++s)
                basec += (int)__popcll(__ballot(key[s] == t) & ltm);
            int own = 0;
            #pragma unroll
            for (int s = 0; s < 8; ++s) {
                const bool eq = (key[s] == t);
                if (key[s] > t || (eq && (basec + own) < need[r]))
                    fl[s] |= (1 << r);
                own += eq ? 1 : 0;
            }
        }
    }

    // ---- softmax denominators (shift-invariant: no max subtraction) ----
    float z0 = 0.f, z1 = 0.f, z2 = 0.f, z3 = 0.f;
    #pragma unroll
    for (int s = 0; s < 8; ++s) {
        z0 += (fl[s] & 1) ? eo[s] : 0.f;
        z1 += (fl[s] & 2) ? eo[s] : 0.f;
        z2 += (fl[s] & 4) ? eo[s] : 0.f;
        z3 += (fl[s] & 8) ? eo[s] : 0.f;
    }
    #pragma unroll
    for (int off = 32; off >= 1; off >>= 1) {
        z0 += __shfl_xor(z0, off, 64);
        z1 += __shfl_xor(z1, off, 64);
        z2 += __shfl_xor(z2, off, 64);
        z3 += __shfl_xor(z3, off, 64);
    }

    // fast reciprocal: ~1ulp rel error, negligible vs output scale
    const float wz0 = w1p[0] * __builtin_amdgcn_rcpf(z0);
    const float wz1 = w2p[0] * __builtin_amdgcn_rcpf(z1);
    const float wz2 = w3p[0] * __builtin_amdgcn_rcpf(z2);
    const float wz3 = w4p[0] * __builtin_amdgcn_rcpf(z3);

    // ---- epilogue ----
    float res[8];
    #pragma unroll
    for (int s = 0; s < 8; ++s) {
        float c = 0.f;
        c += (fl[s] & 1) ? wz0 : 0.f;
        c += (fl[s] & 2) ? wz1 : 0.f;
        c += (fl[s] & 4) ? wz2 : 0.f;
        c += (fl[s] & 8) ? wz3 : 0.f;
        res[s] = eo[s] * c;
    }
    *reinterpret_cast<float4*>(out + base)     = make_float4(res[0], res[1], res[2], res[3]);
    *reinterpret_cast<float4*>(out + base + 4) = make_float4(res[4], res[5], res[6], res[7]);
}

extern "C" void kernel_launch(void* const* d_in, const int* in_sizes, int n_in,
                              void* d_out, int out_size, void* d_ws, size_t ws_size,
                              hipStream_t stream) {
    const float* attn = (const float*)d_in[0];
    const float* w1   = (const float*)d_in[1];
    const float* w2   = (const float*)d_in[2];
    const float* w3   = (const float*)d_in[3];
    const float* w4   = (const float*)d_in[4];
    float* out = (float*)d_out;

    int rows = in_sizes[0] / ROW_C;      // 8*8*512 = 32768
    int blocks = (rows + 3) / 4;         // 4 waves (rows) per 256-thread block
    topk_ms_kernel<<<blocks, 256, 0, stream>>>(attn, w1, w2, w3, w4, out);
}

// Round 2
// 128.861 us; speedup vs baseline: 1.1513x; 1.0585x over previous
//
#include <hip/hip_runtime.h>
#include <math.h>

#define ROW_C 512
#define NBIN 2048
#define NPACK (NBIN / 2)   // two 16-bit counters per int -> 1024 ints = 4KB/wave

// One wave per row, 8 elements/lane. Selection of the K-th largest for
// K in {256,341,384,409}:
//  1. value-uniform 2048-bin histogram over octave [8,16) (clamp +-3.90625,
//     +12.0 -> bin width 1/256; bits [22:12] monotone). Packed u16x2
//     counters, per-wave LDS, XOR-swizzled so int4 reads/writes are
//     bank-conflict-free. Clamped values land in bins 24 / 2024.
//  2. per-lane packed totals + 6-step cross-lane scan; ballots locate each
//     rank's owner lane. Crossing scan is 16-LANES-PER-RANK (not 4 lanes):
//     each lane loads ONE word of its rank's owner, 4-step segmented scan,
//     ballot finds the crossing word -> bsel, R-within-bin, all-in predicate.
//  3. nested-set threshold unification: every rank reduces to a FLOAT
//     threshold t_r (all-in -> exact reconstructed bin lower edge, bin 24 ->
//     -inf; partial bin -> exact tail wave-max value). Since top-K sets are
//     nested, t1>=t2>=t3>=t4, membership = x>=t_r, and the epilogue
//     coefficient is a 4-deep cndmask chain into prefix sums of wz.
//  4. rare exact-duplicate index-tiebreak -> wave-uniform fallback to the
//     general fl-bitmask path (matches jax.lax.top_k lowest-index rule).
// Softmax shift term omitted (shift-invariant, |x| small). No __syncthreads
// (wave-private LDS, in-order DS pipe). Assumes finite inputs (no NaN/inf).
__global__ __launch_bounds__(256) void topk_ms_kernel(
    const float* __restrict__ attn,
    const float* __restrict__ w1p, const float* __restrict__ w2p,
    const float* __restrict__ w3p, const float* __restrict__ w4p,
    float* __restrict__ out)
{
    __shared__ __align__(16) unsigned hist_all[4][NPACK];

    const int lane = threadIdx.x & 63;
    const int wv   = threadIdx.x >> 6;
    unsigned* h = hist_all[wv];
    int4* hv = (int4*)h;

    const long long row  = (long long)blockIdx.x * 4 + wv;
    const long long base = row * ROW_C + lane * 8;

    const float4 A = *reinterpret_cast<const float4*>(attn + base);
    const float4 B = *reinterpret_cast<const float4*>(attn + base + 4);
    float x[8] = {A.x, A.y, A.z, A.w, B.x, B.y, B.z, B.w};

    int bin[8];
    float eo[8];
    #pragma unroll
    for (int s = 0; s < 8; ++s) {
        const float y = __builtin_amdgcn_fmed3f(x[s], -3.90625f, 3.90625f) + 12.0f;
        bin[s] = (int)((__float_as_uint(y) >> 12) & 0x7FFu);   // monotone, width 1/256
        eo[s] = __expf(x[s]);
    }

    // ---- zero histogram (1024 ints, conflict-free int4 stores) ----
    {
        const int4 z = make_int4(0, 0, 0, 0);
        hv[lane] = z; hv[lane + 64] = z; hv[lane + 128] = z; hv[lane + 192] = z;
    }

    // ---- histogram: packed atomic adds, swizzled addressing ----
    // logical word j -> physical j ^ (bits[7:5] -> [4:2]); preserves 4-int blocks.
    #pragma unroll
    for (int s = 0; s < 8; ++s) {
        const int j  = bin[s] >> 1;
        const int ph = j ^ ((j >> 3) & 0x1C);
        atomicAdd(&h[ph], (bin[s] & 1) ? 0x10000u : 1u);
    }

    // ---- per-lane raw totals of own 32 bins ----
    unsigned ps = 0;
    #pragma unroll
    for (int k = 0; k < 4; ++k) {
        const int b  = 4 * lane + k;
        const int pb = b ^ ((b >> 3) & 7);
        const int4 v = hv[pb];
        ps += (unsigned)v.x + (unsigned)v.y + (unsigned)v.z + (unsigned)v.w;
    }
    const unsigned tot = (ps & 0xFFFFu) + (ps >> 16);

    // cross-lane inclusive scan of lane totals
    unsigned incl = tot;
    #pragma unroll
    for (int off = 1; off < 64; off <<= 1) {
        const unsigned t = __shfl_up(incl, off, 64);
        incl += (lane >= off) ? t : 0u;
    }
    const unsigned excl = incl - tot;

    // ---- owner lane per rank: first lane with incl >= T, T = 513-K ----
    const unsigned long long Ba = __ballot(incl >= 257u);
    const unsigned long long Bb = __ballot(incl >= 172u);
    const unsigned long long Bc = __ballot(incl >= 129u);
    const unsigned long long Bd = __ballot(incl >= 104u);
    const int l0 = __ffsll(Ba) - 1, l1 = __ffsll(Bb) - 1,
              l2 = __ffsll(Bc) - 1, l3 = __ffsll(Bd) - 1;

    // ---- crossing scan: 16 lanes per rank, one histogram word each ----
    const int r = lane >> 4;        // rank handled by this lane's group
    const int i = lane & 15;        // word slot within the owner's 16 words
    const int lsel = (r == 0) ? l0 : (r == 1) ? l1 : (r == 2) ? l2 : l3;
    const int Tr   = (r == 0) ? 257 : (r == 1) ? 172 : (r == 2) ? 129 : 104;
    const int Kr   = (r == 0) ? 256 : (r == 1) ? 341 : (r == 2) ? 384 : 409;
    const unsigned exl = __shfl(excl, lsel, 64);   // global prefix before owner

    const int jw = (lsel << 4) + i;                // logical word index
    const int pw = jw ^ ((jw >> 3) & 0x1C);        // same swizzle as atomics
    const unsigned w0 = h[pw];
    const unsigned q  = w0 + (w0 << 16);           // packed (even, even+odd)
    const unsigned wt = q >> 16;                   // word total
    unsigned sc = wt;                              // 4-step segmented scan
    #pragma unroll
    for (int off = 1; off < 16; off <<= 1) {
        const unsigned t = __shfl_up(sc, off, 64);
        sc += (i >= off) ? t : 0u;
    }
    const unsigned ebase = exl + (sc - wt);        // global prefix before word
    const int      phi   = (int)(ebase + wt);      // global incl prefix at word
    const unsigned long long CB = __ballot(phi >= Tr);
    const int js = __ffs((unsigned)(CB >> (r << 4))) - 1;   // crossing word
    const unsigned q_w  = __shfl(q, (r << 4) + js, 64);
    const unsigned eb_w = __shfl(ebase, (r << 4) + js, 64);

    const int  plo  = (int)(eb_w + (q_w & 0xFFFFu));   // pref at even bin
    const int  phw  = (int)(eb_w + (q_w >> 16));       // pref at odd bin
    const bool ev   = (plo >= Tr);
    const int  bsel = (((lsel << 4) + js) << 1) + (ev ? 0 : 1);
    const int  locp = ev ? plo : phw;              // global pref at bsel
    const int  prvp = ev ? (int)eb_w : plo;        // global pref at bsel-1
    const int  Rr   = Kr - 512 + locp;             // rank within bin, >=1
    const int  alin = (prvp == Tr - 1) ? 1 : 0;    // whole bin admitted
    // exact lower edge of bin bsel in x-space (bin width 2^-8, exact fp32)
    float tje = __uint_as_float((unsigned)(bsel + 0x41000) << 12) - 12.0f;
    tje = (bsel <= 24) ? -__builtin_inff() : tje;  // low clamp bin: admit all
    const unsigned pk = ((unsigned)bsel << 11) | ((unsigned)alin << 10) | (unsigned)Rr;

    // ---- broadcast per-rank results to every lane ----
    int b_[4], R_[4], al_[4]; float tthr[4];
    #pragma unroll
    for (int rr = 0; rr < 4; ++rr) {
        const unsigned v = __shfl(pk, rr << 4, 64);
        tthr[rr] = __shfl(tje, rr << 4, 64);
        b_[rr]  = (int)(v >> 11);
        al_[rr] = (int)((v >> 10) & 1u);
        R_[rr]  = (int)(v & 0x3FFu);
    }

    // ---- exact tail only for partially-admitted bins -> float threshold ----
    int needv[4] = {0,0,0,0}, cntv[4] = {0,0,0,0};
    bool anytb = false;
    const float NINF = -__builtin_inff();
    #pragma unroll
    for (int rr = 0; rr < 4; ++rr) {
        if (!al_[rr]) {                            // wave-uniform branch
            float cm[8];
            #pragma unroll
            for (int s = 0; s < 8; ++s)
                cm[s] = (bin[s] == b_[rr]) ? x[s] : NINF;
            int R = R_[rr];
            float t; int c;
            while (true) {
                float mk = cm[0];
                #pragma unroll
                for (int s = 1; s < 8; ++s) mk = fmaxf(mk, cm[s]);
                #pragma unroll
                for (int off = 32; off >= 1; off >>= 1)
                    mk = fmaxf(mk, __shfl_xor(mk, off, 64));
                t = mk;
                c = 0;
                #pragma unroll
                for (int s = 0; s < 8; ++s)
                    c += (int)__popcll(__ballot(cm[s] == t));
                if (c >= R) break;
                R -= c;
                #pragma unroll
                for (int s = 0; s < 8; ++s)
                    cm[s] = (cm[s] == t) ? NINF : cm[s];
            }
            tthr[rr] = t; needv[rr] = R; cntv[rr] = c;
            anytb = anytb || (c != R);             // index tiebreak needed?
        }
    }

    float res[8];
    if (!anytb) {
        // ---- fast path: 4 nested float thresholds t1>=t2>=t3>=t4 ----
        const float t1 = tthr[0], t2 = tthr[1], t3 = tthr[2], t4 = tthr[3];
        float z0 = 0.f, z1 = 0.f, z2 = 0.f, z3 = 0.f;
        #pragma unroll
        for (int s = 0; s < 8; ++s) {
            z0 += (x[s] >= t1) ? eo[s] : 0.f;
            z1 += (x[s] >= t2) ? eo[s] : 0.f;
            z2 += (x[s] >= t3) ? eo[s] : 0.f;
            z3 += (x[s] >= t4) ? eo[s] : 0.f;
        }
        #pragma unroll
        for (int off = 32; off >= 1; off >>= 1) {
            z0 += __shfl_xor(z0, off, 64);
            z1 += __shfl_xor(z1, off, 64);
            z2 += __shfl_xor(z2, off, 64);
            z3 += __shfl_xor(z3, off, 64);
        }
        const float wz0 = w1p[0] * __builtin_amdgcn_rcpf(z0);
        const float wz1 = w2p[0] * __builtin_amdgcn_rcpf(z1);
        const float wz2 = w3p[0] * __builtin_amdgcn_rcpf(z2);
        const float wz3 = w4p[0] * __builtin_amdgcn_rcpf(z3);
        const float u4 = wz3, u3 = u4 + wz2, u2 = u3 + wz1, u1 = u2 + wz0;
        #pragma unroll
        for (int s = 0; s < 8; ++s) {
            float c = (x[s] >= t1) ? u1 : u2;      // category coefficient
            c = (x[s] >= t2) ? c : u3;
            c = (x[s] >= t3) ? c : u4;
            c = (x[s] >= t4) ? c : 0.f;
            res[s] = eo[s] * c;
        }
    } else {
        // ---- slow path (exact-duplicate tiebreak): general fl bitmask ----
        int fl[8] = {0, 0, 0, 0, 0, 0, 0, 0};
        #pragma unroll
        for (int rr = 0; rr < 4; ++rr) {
            const float t = tthr[rr];
            if (al_[rr] || needv[rr] == cntv[rr]) {
                #pragma unroll
                for (int s = 0; s < 8; ++s)
                    fl[s] |= ((int)(x[s] >= t)) << rr;
            } else {                                // admit lowest original idx
                const unsigned long long ltm = (1ull << lane) - 1ull;
                int basec = 0;
                #pragma unroll
                for (int s = 0; s < 8; ++s)
                    basec += (int)__popcll(__ballot(x[s] == t) & ltm);
                int own = 0;
                #pragma unroll
                for (int s = 0; s < 8; ++s) {
                    const bool eq = (x[s] == t);
                    if (x[s] > t || (eq && (basec + own) < needv[rr]))
                        fl[s] |= (1 << rr);
                    own += eq ? 1 : 0;
                }
            }
        }
        float z0 = 0.f, z1 = 0.f, z2 = 0.f, z3 = 0.f;
        #pragma unroll
        for (int s = 0; s < 8; ++s) {
            z0 += (fl[s] & 1) ? eo[s] : 0.f;
            z1 += (fl[s] & 2) ? eo[s] : 0.f;
            z2 += (fl[s] & 4) ? eo[s] : 0.f;
            z3 += (fl[s] & 8) ? eo[s] : 0.f;
        }
        #pragma unroll
        for (int off = 32; off >= 1; off >>= 1) {
            z0 += __shfl_xor(z0, off, 64);
            z1 += __shfl_xor(z1, off, 64);
            z2 += __shfl_xor(z2, off, 64);
            z3 += __shfl_xor(z3, off, 64);
        }
        const float wz0 = w1p[0] * __builtin_amdgcn_rcpf(z0);
        const float wz1 = w2p[0] * __builtin_amdgcn_rcpf(z1);
        const float wz2 = w3p[0] * __builtin_amdgcn_rcpf(z2);
        const float wz3 = w4p[0] * __builtin_amdgcn_rcpf(z3);
        #pragma unroll
        for (int s = 0; s < 8; ++s) {
            float c = 0.f;
            c += (fl[s] & 1) ? wz0 : 0.f;
            c += (fl[s] & 2) ? wz1 : 0.f;
            c += (fl[s] & 4) ? wz2 : 0.f;
            c += (fl[s] & 8) ? wz3 : 0.f;
            res[s] = eo[s] * c;
        }
    }

    *reinterpret_cast<float4*>(out + base)     = make_float4(res[0], res[1], res[2], res[3]);
    *reinterpret_cast<float4*>(out + base + 4) = make_float4(res[4], res[5], res[6], res[7]);
}

extern "C" void kernel_launch(void* const* d_in, const int* in_sizes, int n_in,
                              void* d_out, int out_size, void* d_ws, size_t ws_size,
                              hipStream_t stream) {
    const float* attn = (const float*)d_in[0];
    const float* w1   = (const float*)d_in[1];
    const float* w2   = (const float*)d_in[2];
    const float* w3   = (const float*)d_in[3];
    const float* w4   = (const float*)d_in[4];
    float* out = (float*)d_out;

    int rows = in_sizes[0] / ROW_C;      // 8*8*512 = 32768
    int blocks = (rows + 3) / 4;         // 4 waves (rows) per 256-thread block
    topk_ms_kernel<<<blocks, 256, 0, stream>>>(attn, w1, w2, w3, w4, out);
}

// Round 3
// 122.298 us; speedup vs baseline: 1.2131x; 1.0537x over previous
//
#include <hip/hip_runtime.h>
#include <math.h>

#define ROW_C 512
#define NBIN 2048
#define NPACK (NBIN / 2)   // two 16-bit counters per int -> 1024 ints = 4KB/wave

// One wave per row, 8 elements/lane. Selection of the K-th largest for
// K in {256,341,384,409}:
//  1. value-uniform 2048-bin histogram over octave [8,16) (clamp +-3.90625,
//     +12.0 -> bin width 1/256; bits [22:12] monotone). Packed u16x2
//     counters, per-wave LDS, XOR-swizzled so int4 reads/writes are
//     bank-conflict-free. Clamped values land in bins 24 / 2024.
//  2. per-lane packed totals + DPP 64-lane inclusive scan (canonical
//     row_shr/row_bcast sequence, 0 DS ops); ballots locate each rank's
//     owner lane. Crossing scan: 16 lanes per rank, one histogram word each,
//     4-step DPP row scan, ballot finds crossing word -> bsel, R-within-bin,
//     all-in predicate. Per-rank results broadcast via v_readlane (SGPR).
//  3. nested-set threshold unification: every rank reduces to a FLOAT
//     threshold t_r in an SGPR (all-in -> exact reconstructed bin lower
//     edge, bin<=24 -> -inf; partial bin -> exact tail wave-max value via
//     DPP max-reduce + readlane). t1>=t2>=t3>=t4; membership = x>=t_r;
//     epilogue coefficient = 4-deep cndmask chain into prefix sums of wz.
//  4. rare exact-duplicate index-tiebreak -> wave-uniform fallback to the
//     general fl-bitmask path (matches jax.lax.top_k lowest-index rule).
// All scans/reductions are DPP (no ds_bpermute): the only DS traffic left is
// zero(4) + atomics(8) + totals(4) + 1 word read + 3 runtime-lane shuffles.
// Softmax shift term omitted (shift-invariant, |x| small). No __syncthreads
// (wave-private LDS, in-order DS pipe). Assumes finite inputs (no NaN/inf).

static __device__ __forceinline__ unsigned scan64_add(unsigned v) {
    // canonical GFX9 wave64 inclusive add-scan (identity 0)
    int x = (int)v;
    x += __builtin_amdgcn_update_dpp(0, x, 0x111, 0xF, 0xF, false); // row_shr:1
    x += __builtin_amdgcn_update_dpp(0, x, 0x112, 0xF, 0xF, false); // row_shr:2
    x += __builtin_amdgcn_update_dpp(0, x, 0x114, 0xF, 0xE, false); // row_shr:4
    x += __builtin_amdgcn_update_dpp(0, x, 0x118, 0xF, 0xC, false); // row_shr:8
    x += __builtin_amdgcn_update_dpp(0, x, 0x142, 0xA, 0xF, false); // row_bcast:15
    x += __builtin_amdgcn_update_dpp(0, x, 0x143, 0xC, 0xF, false); // row_bcast:31
    return (unsigned)x;
}

static __device__ __forceinline__ unsigned scan16_add(unsigned v) {
    // inclusive add-scan within each 16-lane row (our rank groups)
    int x = (int)v;
    x += __builtin_amdgcn_update_dpp(0, x, 0x111, 0xF, 0xF, false);
    x += __builtin_amdgcn_update_dpp(0, x, 0x112, 0xF, 0xF, false);
    x += __builtin_amdgcn_update_dpp(0, x, 0x114, 0xF, 0xE, false);
    x += __builtin_amdgcn_update_dpp(0, x, 0x118, 0xF, 0xC, false);
    return (unsigned)x;
}

static __device__ __forceinline__ float wave_fadd_red(float v) {
    // wave sum -> uniform (via lane 63); scan order, identity 0
    float t;
    t = __int_as_float(__builtin_amdgcn_update_dpp(0, __float_as_int(v), 0x111, 0xF, 0xF, false)); v += t;
    t = __int_as_float(__builtin_amdgcn_update_dpp(0, __float_as_int(v), 0x112, 0xF, 0xF, false)); v += t;
    t = __int_as_float(__builtin_amdgcn_update_dpp(0, __float_as_int(v), 0x114, 0xF, 0xE, false)); v += t;
    t = __int_as_float(__builtin_amdgcn_update_dpp(0, __float_as_int(v), 0x118, 0xF, 0xC, false)); v += t;
    t = __int_as_float(__builtin_amdgcn_update_dpp(0, __float_as_int(v), 0x142, 0xA, 0xF, false)); v += t;
    t = __int_as_float(__builtin_amdgcn_update_dpp(0, __float_as_int(v), 0x143, 0xC, 0xF, false)); v += t;
    return __int_as_float(__builtin_amdgcn_readlane(__float_as_int(v), 63));
}

static __device__ __forceinline__ float wave_fmax_red(float v) {
    // wave max -> uniform (via lane 63); identity -inf
    const int NI = (int)0xFF800000;
    float t;
    t = __int_as_float(__builtin_amdgcn_update_dpp(NI, __float_as_int(v), 0x111, 0xF, 0xF, false)); v = fmaxf(v, t);
    t = __int_as_float(__builtin_amdgcn_update_dpp(NI, __float_as_int(v), 0x112, 0xF, 0xF, false)); v = fmaxf(v, t);
    t = __int_as_float(__builtin_amdgcn_update_dpp(NI, __float_as_int(v), 0x114, 0xF, 0xE, false)); v = fmaxf(v, t);
    t = __int_as_float(__builtin_amdgcn_update_dpp(NI, __float_as_int(v), 0x118, 0xF, 0xC, false)); v = fmaxf(v, t);
    t = __int_as_float(__builtin_amdgcn_update_dpp(NI, __float_as_int(v), 0x142, 0xA, 0xF, false)); v = fmaxf(v, t);
    t = __int_as_float(__builtin_amdgcn_update_dpp(NI, __float_as_int(v), 0x143, 0xC, 0xF, false)); v = fmaxf(v, t);
    return __int_as_float(__builtin_amdgcn_readlane(__float_as_int(v), 63));
}

__global__ __launch_bounds__(256) void topk_ms_kernel(
    const float* __restrict__ attn,
    const float* __restrict__ w1p, const float* __restrict__ w2p,
    const float* __restrict__ w3p, const float* __restrict__ w4p,
    float* __restrict__ out)
{
    __shared__ __align__(16) unsigned hist_all[4][NPACK];

    const int lane = threadIdx.x & 63;
    const int wv   = threadIdx.x >> 6;
    unsigned* h = hist_all[wv];
    int4* hv = (int4*)h;

    const long long row  = (long long)blockIdx.x * 4 + wv;
    const long long base = row * ROW_C + lane * 8;

    const float4 A = *reinterpret_cast<const float4*>(attn + base);
    const float4 B = *reinterpret_cast<const float4*>(attn + base + 4);
    float x[8] = {A.x, A.y, A.z, A.w, B.x, B.y, B.z, B.w};

    int bin[8];
    float eo[8];
    #pragma unroll
    for (int s = 0; s < 8; ++s) {
        const float y = __builtin_amdgcn_fmed3f(x[s], -3.90625f, 3.90625f) + 12.0f;
        bin[s] = (int)((__float_as_uint(y) >> 12) & 0x7FFu);   // monotone, width 1/256
        eo[s] = __expf(x[s]);
    }

    // ---- zero histogram (1024 ints, conflict-free int4 stores) ----
    {
        const int4 z = make_int4(0, 0, 0, 0);
        hv[lane] = z; hv[lane + 64] = z; hv[lane + 128] = z; hv[lane + 192] = z;
    }

    // ---- histogram: packed atomic adds, swizzled addressing ----
    // logical word j -> physical j ^ (bits[7:5] -> [4:2]); preserves 4-int blocks.
    #pragma unroll
    for (int s = 0; s < 8; ++s) {
        const int j  = bin[s] >> 1;
        const int ph = j ^ ((j >> 3) & 0x1C);
        atomicAdd(&h[ph], (bin[s] & 1) ? 0x10000u : 1u);
    }

    // ---- per-lane raw totals of own 32 bins ----
    unsigned ps = 0;
    #pragma unroll
    for (int k = 0; k < 4; ++k) {
        const int b  = 4 * lane + k;
        const int pb = b ^ ((b >> 3) & 7);
        const int4 v = hv[pb];
        ps += (unsigned)v.x + (unsigned)v.y + (unsigned)v.z + (unsigned)v.w;
    }
    const unsigned tot = (ps & 0xFFFFu) + (ps >> 16);

    // cross-lane inclusive scan of lane totals (DPP, 0 DS)
    const unsigned incl = scan64_add(tot);
    const unsigned excl = incl - tot;

    // ---- owner lane per rank: first lane with incl >= T, T = 513-K ----
    const unsigned long long Ba = __ballot(incl >= 257u);
    const unsigned long long Bb = __ballot(incl >= 172u);
    const unsigned long long Bc = __ballot(incl >= 129u);
    const unsigned long long Bd = __ballot(incl >= 104u);
    const int l0 = __ffsll(Ba) - 1, l1 = __ffsll(Bb) - 1,
              l2 = __ffsll(Bc) - 1, l3 = __ffsll(Bd) - 1;

    // ---- crossing scan: 16 lanes per rank, one histogram word each ----
    const int r = lane >> 4;        // rank handled by this lane's group
    const int lsel = (r == 0) ? l0 : (r == 1) ? l1 : (r == 2) ? l2 : l3;
    const int Tr   = (r == 0) ? 257 : (r == 1) ? 172 : (r == 2) ? 129 : 104;
    const int Kr   = (r == 0) ? 256 : (r == 1) ? 341 : (r == 2) ? 384 : 409;
    const unsigned exl = __shfl(excl, lsel, 64);   // global prefix before owner

    const int jw = (lsel << 4) + (lane & 15);      // logical word index
    const int pw = jw ^ ((jw >> 3) & 0x1C);        // same swizzle as atomics
    const unsigned w0 = h[pw];
    const unsigned q  = w0 + (w0 << 16);           // packed (even, even+odd)
    const unsigned wt = q >> 16;                   // word total
    const unsigned sc = scan16_add(wt);            // DPP row scan (0 DS)
    const unsigned ebase = exl + (sc - wt);        // global prefix before word
    const int      phi   = (int)(ebase + wt);      // global incl prefix at word
    const unsigned long long CB = __ballot(phi >= Tr);
    const int js = __ffs((unsigned)(CB >> (r << 4))) - 1;   // crossing word
    const unsigned q_w  = __shfl(q, (r << 4) + js, 64);
    const unsigned eb_w = __shfl(ebase, (r << 4) + js, 64);

    const int  plo  = (int)(eb_w + (q_w & 0xFFFFu));   // pref at even bin
    const int  phw  = (int)(eb_w + (q_w >> 16));       // pref at odd bin
    const bool ev   = (plo >= Tr);
    const int  bsel = (((lsel << 4) + js) << 1) + (ev ? 0 : 1);
    const int  locp = ev ? plo : phw;              // global pref at bsel
    const int  prvp = ev ? (int)eb_w : plo;        // global pref at bsel-1
    const int  Rr   = Kr - 512 + locp;             // rank within bin, >=1
    const int  alin = (prvp == Tr - 1) ? 1 : 0;    // whole bin admitted
    const unsigned pk = ((unsigned)bsel << 11) | ((unsigned)alin << 10) | (unsigned)Rr;

    // ---- per-rank results -> SGPRs via readlane at lanes 0/16/32/48 ----
    int b_[4], R_[4], al_[4]; float tthr[4];
    const float NINF = -__builtin_inff();
    {
        const unsigned v0 = (unsigned)__builtin_amdgcn_readlane((int)pk, 0);
        const unsigned v1 = (unsigned)__builtin_amdgcn_readlane((int)pk, 16);
        const unsigned v2 = (unsigned)__builtin_amdgcn_readlane((int)pk, 32);
        const unsigned v3 = (unsigned)__builtin_amdgcn_readlane((int)pk, 48);
        const unsigned vv[4] = {v0, v1, v2, v3};
        #pragma unroll
        for (int rr = 0; rr < 4; ++rr) {
            b_[rr]  = (int)(vv[rr] >> 11);
            al_[rr] = (int)((vv[rr] >> 10) & 1u);
            R_[rr]  = (int)(vv[rr] & 0x3FFu);
            // exact lower edge of bin in x-space (width 2^-8, exact fp32)
            float t = __uint_as_float((unsigned)(b_[rr] + 0x41000) << 12) - 12.0f;
            tthr[rr] = (b_[rr] <= 24) ? NINF : t;  // low clamp bin: admit all
        }
    }

    // ---- exact tail only for partially-admitted bins -> float threshold ----
    int needv[4] = {0,0,0,0}, cntv[4] = {0,0,0,0};
    bool anytb = false;
    #pragma unroll
    for (int rr = 0; rr < 4; ++rr) {
        if (!al_[rr]) {                            // wave-uniform branch
            float cm[8];
            #pragma unroll
            for (int s = 0; s < 8; ++s)
                cm[s] = (bin[s] == b_[rr]) ? x[s] : NINF;
            int R = R_[rr];
            float t; int c;
            while (true) {
                float mk = cm[0];
                #pragma unroll
                for (int s = 1; s < 8; ++s) mk = fmaxf(mk, cm[s]);
                t = wave_fmax_red(mk);             // DPP + readlane (0 bpermute)
                c = 0;
                #pragma unroll
                for (int s = 0; s < 8; ++s)
                    c += (int)__popcll(__ballot(cm[s] == t));
                if (c >= R) break;
                R -= c;
                #pragma unroll
                for (int s = 0; s < 8; ++s)
                    cm[s] = (cm[s] == t) ? NINF : cm[s];
            }
            tthr[rr] = t; needv[rr] = R; cntv[rr] = c;
            anytb = anytb || (c != R);             // index tiebreak needed?
        }
    }

    float res[8];
    if (!anytb) {
        // ---- fast path: 4 nested float thresholds t1>=t2>=t3>=t4 ----
        const float t1 = tthr[0], t2 = tthr[1], t3 = tthr[2], t4 = tthr[3];
        float z0 = 0.f, z1 = 0.f, z2 = 0.f, z3 = 0.f;
        #pragma unroll
        for (int s = 0; s < 8; ++s) {
            z0 += (x[s] >= t1) ? eo[s] : 0.f;
            z1 += (x[s] >= t2) ? eo[s] : 0.f;
            z2 += (x[s] >= t3) ? eo[s] : 0.f;
            z3 += (x[s] >= t4) ? eo[s] : 0.f;
        }
        const float Z0 = wave_fadd_red(z0);
        const float Z1 = wave_fadd_red(z1);
        const float Z2 = wave_fadd_red(z2);
        const float Z3 = wave_fadd_red(z3);
        const float wz0 = w1p[0] * __builtin_amdgcn_rcpf(Z0);
        const float wz1 = w2p[0] * __builtin_amdgcn_rcpf(Z1);
        const float wz2 = w3p[0] * __builtin_amdgcn_rcpf(Z2);
        const float wz3 = w4p[0] * __builtin_amdgcn_rcpf(Z3);
        const float u4 = wz3, u3 = u4 + wz2, u2 = u3 + wz1, u1 = u2 + wz0;
        #pragma unroll
        for (int s = 0; s < 8; ++s) {
            float c = (x[s] >= t1) ? u1 : u2;      // category coefficient
            c = (x[s] >= t2) ? c : u3;
            c = (x[s] >= t3) ? c : u4;
            c = (x[s] >= t4) ? c : 0.f;
            res[s] = eo[s] * c;
        }
    } else {
        // ---- slow path (exact-duplicate tiebreak): general fl bitmask ----
        int fl[8] = {0, 0, 0, 0, 0, 0, 0, 0};
        #pragma unroll
        for (int rr = 0; rr < 4; ++rr) {
            const float t = tthr[rr];
            if (al_[rr] || needv[rr] == cntv[rr]) {
                #pragma unroll
                for (int s = 0; s < 8; ++s)
                    fl[s] |= ((int)(x[s] >= t)) << rr;
            } else {                                // admit lowest original idx
                const unsigned long long ltm = (1ull << lane) - 1ull;
                int basec = 0;
                #pragma unroll
                for (int s = 0; s < 8; ++s)
                    basec += (int)__popcll(__ballot(x[s] == t) & ltm);
                int own = 0;
                #pragma unroll
                for (int s = 0; s < 8; ++s) {
                    const bool eq = (x[s] == t);
                    if (x[s] > t || (eq && (basec + own) < needv[rr]))
                        fl[s] |= (1 << rr);
                    own += eq ? 1 : 0;
                }
            }
        }
        float z0 = 0.f, z1 = 0.f, z2 = 0.f, z3 = 0.f;
        #pragma unroll
        for (int s = 0; s < 8; ++s) {
            z0 += (fl[s] & 1) ? eo[s] : 0.f;
            z1 += (fl[s] & 2) ? eo[s] : 0.f;
            z2 += (fl[s] & 4) ? eo[s] : 0.f;
            z3 += (fl[s] & 8) ? eo[s] : 0.f;
        }
        const float Z0 = wave_fadd_red(z0);
        const float Z1 = wave_fadd_red(z1);
        const float Z2 = wave_fadd_red(z2);
        const float Z3 = wave_fadd_red(z3);
        const float wz0 = w1p[0] * __builtin_amdgcn_rcpf(Z0);
        const float wz1 = w2p[0] * __builtin_amdgcn_rcpf(Z1);
        const float wz2 = w3p[0] * __builtin_amdgcn_rcpf(Z2);
        const float wz3 = w4p[0] * __builtin_amdgcn_rcpf(Z3);
        #pragma unroll
        for (int s = 0; s < 8; ++s) {
            float c = 0.f;
            c += (fl[s] & 1) ? wz0 : 0.f;
            c += (fl[s] & 2) ? wz1 : 0.f;
            c += (fl[s] & 4) ? wz2 : 0.f;
            c += (fl[s] & 8) ? wz3 : 0.f;
            res[s] = eo[s] * c;
        }
    }

    *reinterpret_cast<float4*>(out + base)     = make_float4(res[0], res[1], res[2], res[3]);
    *reinterpret_cast<float4*>(out + base + 4) = make_float4(res[4], res[5], res[6], res[7]);
}

extern "C" void kernel_launch(void* const* d_in, const int* in_sizes, int n_in,
                              void* d_out, int out_size, void* d_ws, size_t ws_size,
                              hipStream_t stream) {
    const float* attn = (const float*)d_in[0];
    const float* w1   = (const float*)d_in[1];
    const float* w2   = (const float*)d_in[2];
    const float* w3   = (const float*)d_in[3];
    const float* w4   = (const float*)d_in[4];
    float* out = (float*)d_out;

    int rows = in_sizes[0] / ROW_C;      // 8*8*512 = 32768
    int blocks = (rows + 3) / 4;         // 4 waves (rows) per 256-thread block
    topk_ms_kernel<<<blocks, 256, 0, stream>>>(attn, w1, w2, w3, w4, out);
}